// Round 9
// baseline (222.545 us; speedup 1.0000x reference)
//
#include <hip/hip_runtime.h>
#include <stdint.h>

#define B_ 16
#define A_ 9
#define H_ 128
#define W_ 128
#define HW_ (H_*W_)
#define N_ (HW_*A_)          // 147456 proposals per image
#define PRE_ 2000
#define POST_ 300
#define CAND_CAP 4096
#define SEG_ 32              // 2048 / 64 segments for the NMS scan

typedef unsigned int u32;
typedef unsigned long long u64;

// ---- workspace layout (bytes) ----
// [state | hist0 | hist1] zeroed by ONE memsetAsync per launch.
#define OFF_STATE  0ull                               // B*8 u32 (pad to 1024)
#define OFF_HIST0  1024ull                            // B*256 u32 = 16384
#define OFF_HIST1  (OFF_HIST0 + 16384ull)             // B*256 u32 = 16384
#define OFF_KEYS   (OFF_HIST1 + 16384ull)
#define OFF_CAND   (OFF_KEYS + (u64)B_*N_*4)
#define OFF_SELBOX (OFF_CAND + (u64)B_*CAND_CAP*8)
#define OFF_LIVE   (OFF_SELBOX + (u64)B_*PRE_*16)
#define OFF_SUPP   (OFF_LIVE + (u64)B_*32*8)
// end = OFF_SUPP + B*PRE*32*8  (~18.7 MB total)
// NOTE: keys region is dead after collect_kernel; selkey (B*2048*4 = 128KB)
// is overlaid at OFF_KEYS.

__device__ __forceinline__ u32 mono_key(float f) {
    u32 u = __float_as_uint(f);
    return (u & 0x80000000u) ? ~u : (u | 0x80000000u);
}

// wave-level select over a 256-bin histogram: find bin s.t. suffix-count crosses `need`.
// Must be called by a full wave; the matching lane writes {bin, need-above} to out[0..1].
__device__ __forceinline__ void wave_select256(const u32* __restrict__ hh, u32 need,
                                               u32* __restrict__ out) {
    int lane = threadIdx.x & 63;
    uint4 hv = ((const uint4*)hh)[lane];               // bins 4l..4l+3
    u32 psum = hv.x + hv.y + hv.z + hv.w;
    u32 s = psum;                                      // wave-inclusive suffix sum
    #pragma unroll
    for (int off = 1; off < 64; off <<= 1) {
        u32 o = (u32)__shfl_down((int)s, off);
        if (lane + off < 64) s += o;
    }
    u32 S_next = (u32)__shfl_down((int)s, 1);
    if (lane == 63) S_next = 0;
    u32 above[4], cnt[4];
    above[3] = S_next;             cnt[3] = hv.w;
    above[2] = S_next + hv.w;      cnt[2] = hv.z;
    above[1] = above[2] + hv.z;    cnt[1] = hv.y;
    above[0] = above[1] + hv.y;    cnt[0] = hv.x;
    #pragma unroll
    for (int j = 3; j >= 0; --j) {
        if (above[j] < need && above[j] + cnt[j] >= need) {
            out[0] = (u32)(4*lane + j);
            out[1] = need - above[j];
        }
    }
}

// ---------------- stage 1: decode + fg scores + keys + LDS-aggregated 8-bit hist ----------------
// block = 576 threads (wave a=0..8, lane = p offset); coalesced reads AND writes.
__global__ __launch_bounds__(576) void decode_kernel(
        const float* __restrict__ scores,
        const float* __restrict__ deltas,
        const float* __restrict__ anchors,
        const float* __restrict__ im_info,
        float* __restrict__ outprop,
        u32* __restrict__ keys,
        u32* __restrict__ hist0) {
    __shared__ float4 tile[9][65];   // +1 pad
    __shared__ float4 sbase[A_];
    __shared__ u32 h[256];
    int tid = threadIdx.x;
    int a = tid >> 6, lane = tid & 63;
    if (tid < A_) sbase[tid] = ((const float4*)anchors)[tid];  // anchors[p=0] == base anchors
    if (tid < 256) h[tid] = 0;
    __syncthreads();

    int b  = blockIdx.x >> 8;
    int pb = blockIdx.x & 255;
    int p0 = pb << 6;
    int p  = p0 + lane;

    float s0 = scores[((b*2*A_ + a)      << 14) + p];
    float s1 = scores[((b*2*A_ + A_ + a) << 14) + p];
    float m  = fmaxf(s0, s1);
    float e0 = expf(s0 - m);
    float e1 = expf(s1 - m);
    float fg = e1 / (e0 + e1);

    float4 base = sbase[a];
    int ix = p & (W_-1), iy = p >> 7;
    float sx = (float)(ix * 16), sy = (float)(iy * 16);
    float ax1 = base.x + sx, ay1 = base.y + sy, ax2 = base.z + sx, ay2 = base.w + sy;

    float w  = ax2 - ax1 + 1.0f;
    float h_ = ay2 - ay1 + 1.0f;
    float cx = ax1 + 0.5f*w;
    float cy = ay1 + 0.5f*h_;

    const float* dbase = deltas + (u64)(((b*4*A_ + 4*a) << 14) + p);
    float dx = dbase[0];
    float dy = dbase[HW_];
    float dw = dbase[2*HW_];
    float dh = dbase[3*HW_];

    float pcx = dx*w  + cx;
    float pcy = dy*h_ + cy;
    float pw  = expf(dw)*w;
    float ph  = expf(dh)*h_;
    float x1 = pcx - 0.5f*pw, y1 = pcy - 0.5f*ph;
    float x2 = pcx + 0.5f*pw, y2 = pcy + 0.5f*ph;

    float wmax = im_info[b*4 + 1] - 1.0f;
    float hmax = im_info[b*4 + 0] - 1.0f;
    x1 = fminf(fmaxf(x1, 0.0f), wmax);
    y1 = fminf(fmaxf(y1, 0.0f), hmax);
    x2 = fminf(fmaxf(x2, 0.0f), wmax);
    y2 = fminf(fmaxf(y2, 0.0f), hmax);

    tile[a][lane] = make_float4(x1, y1, x2, y2);

    float bw = x2 - x1 + 1.0f;
    float bh = y2 - y1 + 1.0f;
    bool valid = (bw >= 16.0f*im_info[b*4 + 3]) && (bh >= 16.0f*im_info[b*4 + 2]);
    float sc = valid ? fg : -__builtin_inff();
    u32 k = mono_key(sc);
    keys[((u64)(b*A_ + a) << 14) + p] = k;             // coalesced (a,p) layout
    atomicAdd(&h[k >> 24], 1u);                        // LDS-aggregated 8-bit hist
    __syncthreads();

    // coalesced write-back: n = p*9 + a; block covers n in [p0*9, p0*9 + 576)
    int a2 = tid % 9, pl = tid / 9;
    ((float4*)outprop)[(u64)b*N_ + p0*9 + tid] = tile[a2][pl];

    if (tid < 256 && h[tid]) atomicAdd(&hist0[b*256 + tid], h[tid]);
}

// ---------------- stage 2: 16-bit refine histogram (redundant in-block select8) ----------------
__global__ __launch_bounds__(1024) void hist16_kernel(
        const u32* __restrict__ keys, const u32* __restrict__ hist0,
        u32* __restrict__ hist1) {
    int b = blockIdx.x >> 4;
    int slice = blockIdx.x & 15;
    int tid = threadIdx.x;
    __shared__ u32 sel[2];      // {bin8, rem8}
    __shared__ u32 h[256];
    if (tid < 64) wave_select256(hist0 + b*256, (u32)PRE_, sel);
    for (int i = tid; i < 256; i += 1024) h[i] = 0;
    __syncthreads();
    u32 pfx = sel[0];
    const u32* kb = keys + (u64)b*N_ + slice*(N_/16);
    for (int n = tid; n < N_/16; n += 1024) {
        u32 k = kb[n];
        if ((k >> 24) == pfx) atomicAdd(&h[(k >> 16) & 255u], 1u);
    }
    __syncthreads();
    for (int i = tid; i < 256; i += 1024)
        if (h[i]) atomicAdd(&hist1[b*256 + i], h[i]);
}

// ---------------- stage 3: collect all keys >= T (block-aggregated allocation) ----------------
// Candidate order is irrelevant (rank_kernel re-ranks), so positions are
// allocated in bulk: per-thread register key cache + wave scan + LDS block
// scan + ONE global atomicAdd per block (256 total vs ~33k contended RMWs).
__global__ __launch_bounds__(1024) void collect_kernel(
        const u32* __restrict__ keys, const u32* __restrict__ hist0,
        const u32* __restrict__ hist1, u32* __restrict__ state,
        u64* __restrict__ cand) {
    int b = blockIdx.x >> 4;
    int slice = blockIdx.x & 15;
    int tid = threadIdx.x;
    int wave = tid >> 6, lane = tid & 63;
    __shared__ u32 sel8[2], sel16[2];
    __shared__ u32 wbase[16];
    __shared__ u32 s_base;
    if (tid < 64) wave_select256(hist0 + b*256, (u32)PRE_, sel8);
    __syncthreads();
    if (tid < 64) wave_select256(hist1 + b*256, sel8[1], sel16);
    __syncthreads();
    u32 T = (sel8[0] << 24) | (sel16[0] << 16);        // threshold key

    const u32* kb = keys + (u64)b*N_ + slice*(N_/16);
    u64* cb = cand + (u64)b*CAND_CAP;

    // load 9 keys/thread into registers, count matches
    u32 kreg[9];
    int c = 0;
    #pragma unroll
    for (int r = 0; r < 9; ++r) {
        kreg[r] = kb[tid + r*1024];
        c += (kreg[r] >= T) ? 1 : 0;
    }

    // wave inclusive scan of c
    int x = c;
    #pragma unroll
    for (int off = 1; off < 64; off <<= 1) {
        int y = __shfl_up(x, off);
        if (lane >= off) x += y;
    }
    if (lane == 63) wbase[wave] = (u32)x;              // wave total
    __syncthreads();
    if (tid == 0) {
        u32 acc = 0;
        #pragma unroll
        for (int w2 = 0; w2 < 16; ++w2) { u32 t2 = wbase[w2]; wbase[w2] = acc; acc += t2; }
        s_base = acc ? atomicAdd(&state[b*8 + 2], acc) : 0u;
    }
    __syncthreads();

    u32 pos = s_base + wbase[wave] + (u32)(x - c);     // exclusive prefix
    #pragma unroll
    for (int r = 0; r < 9; ++r) {
        if (kreg[r] >= T) {
            int idx = slice*(N_/16) + tid + r*1024;
            u32 n = (u32)((idx & (HW_-1))*A_ + (idx >> 14));  // n = p*9 + a
            if (pos < CAND_CAP) cb[pos] = ((u64)kreg[r] << 32) | (u32)(~n);
            pos++;
        }
    }
}

// ---------------- stage 4: rank-and-scatter (replaces bitonic sort) ----------------
// rank[i] = #{j : cand[j] > cand[i]} over the stored candidates (u64s are
// distinct: low word carries ~n). Scatter selbox[rank] directly. Barrier-free
// O(cnt^2) spread over B*16 blocks = all 256 CUs; LDS reads are wave-uniform
// broadcasts. Winners also record selkey[rank] for the live-word build in scan.
__global__ __launch_bounds__(1024) void rank_kernel(
        const u64* __restrict__ cand, const u32* __restrict__ state,
        const float* __restrict__ outprop,
        float4* __restrict__ selbox, u32* __restrict__ selkey) {
    int bi = blockIdx.x;               // B*16 blocks
    int b = bi >> 4, chunk = bi & 15;
    int tid = threadIdx.x;
    int q = tid >> 8, ti = tid & 255;  // 4 j-quarters x 256 owned candidates
    __shared__ __align__(16) u64 sc[CAND_CAP];
    __shared__ u32 prank[256];

    u32 cnt = state[b*8 + 2];
    if (cnt > CAND_CAP) cnt = CAND_CAP;
    const u64* cb = cand + (u64)b*CAND_CAP;
    for (int j = tid; j < CAND_CAP; j += 1024) sc[j] = (j < (int)cnt) ? cb[j] : 0ull;
    if (tid < 256) prank[tid] = 0;
    __syncthreads();

    int i = (chunk << 8) + ti;
    u64 mine = sc[i];

    // j-quarter over ulonglong2 pairs covering [0, cnt) (pad region is 0)
    int pairs = ((int)cnt + 1) >> 1;
    int pq = (pairs + 3) >> 2;
    int p0 = q * pq;
    int p1 = p0 + pq; if (p1 > pairs) p1 = pairs;
    const ulonglong2* sl = (const ulonglong2*)sc;
    u32 c = 0;
    #pragma unroll 8
    for (int p = p0; p < p1; ++p) {
        ulonglong2 v = sl[p];          // wave-uniform address -> LDS broadcast
        c += (v.x > mine) ? 1u : 0u;
        c += (v.y > mine) ? 1u : 0u;
    }
    if (c) atomicAdd(&prank[ti], c);
    __syncthreads();

    if (q == 0 && i < (int)cnt) {
        u32 rank = prank[ti];
        if (rank < PRE_) {
            u32 n = ~(u32)mine;
            float4 box = ((const float4*)outprop)[(u64)b*N_ + n];
            selbox[(u64)b*PRE_ + rank] = box;
            selkey[b*2048 + rank] = (u32)(mine >> 32);
        }
    }
}

// ---------------- stage 5: upper-triangle IoU suppression bitmask ----------------
// Greedy NMS only reads supp[r][j] for j > r (reference masks ar > i), and
// scan_kernel's eager-apply only reads future words; diag words are always
// inside the strip's starting chunk (256*floor(r/256) <= 64*floor(r/64)).
// So each 8-row strip starts at chunk c0 = rbase>>8: 57% of the chunk work.
// Division is replaced by an EXACT margin test: m = fma(-t, union, inter);
// |m| > 2.0f provably matches fl32(inter/union) > t (union <= 8.4e6 ->
// |q - t| > 2.4e-7, beyond the f32 quotient rounding band). Rare boundary
// lanes fall back to the exact division (wave-coherent branch).
__global__ __launch_bounds__(256) void iou_kernel(
        const float4* __restrict__ selbox, const float* __restrict__ thrp,
        u64* __restrict__ supp) {
    int bi = blockIdx.x;             // B * 250 blocks, 8 rows each
    int b = bi / 250;
    int rbase = (bi % 250) * 8;
    int c0 = rbase >> 8;             // first column chunk (covers full diag word)
    int tid = threadIdx.x;
    __shared__ float4 box[PRE_];
    for (int i = (c0 << 8) + tid; i < PRE_; i += 256) box[i] = selbox[(u64)b*PRE_ + i];
    __syncthreads();
    float thresh = thrp[0];
    int wv = tid >> 6, lane = tid & 63;

    float4 p[8]; float ai[8];
    #pragma unroll
    for (int r = 0; r < 8; ++r) {
        p[r]  = box[rbase + r];
        ai[r] = (p[r].z - p[r].x + 1.f) * (p[r].w - p[r].y + 1.f);
    }
    for (int c = c0; c < 8; ++c) {
        int j = c*256 + tid;
        bool inb = (j < PRE_);
        float4 q = box[inb ? j : 0];
        float aj = (q.z - q.x + 1.f) * (q.w - q.y + 1.f);
        #pragma unroll
        for (int r = 0; r < 8; ++r) {
            float iw = fminf(p[r].z, q.z) - fmaxf(p[r].x, q.x) + 1.f;
            float ih = fminf(p[r].w, q.w) - fmaxf(p[r].y, q.y) + 1.f;
            float inter = fmaxf(iw, 0.f) * ih;   // ih<0 -> inter<=0 -> pred false (exact)
            float su = ai[r] + aj;
            float un = su - inter;               // same assoc as reference
            float m  = __fmaf_rn(-thresh, un, inter);
            bool pred = m > 0.0f;
            if (__any(fabsf(m) <= 2.0f)) {       // rare: exact boundary resolve
                pred = (inter / un) > thresh;
            }
            pred = pred && inb;
            u64 ball = __ballot(pred);
            if (lane == 0)
                supp[((u64)(b*PRE_ + rbase + r))*32 + (c*4 + wv)] = ball;
        }
    }
}

// ---------------- stage 6: role-split pipelined greedy scan ----------------
// ROUND-8: two fixes to wave 0's critical path, which was invariant across
// r5-r7 (~43.5us):
// (a) wave 0 issues NO global loads. Staging is done by waves 1-3 only
//     (192 threads x 11 words). __syncthreads drains vmcnt per-wave
//     (s_waitcnt vmcnt(0) before s_barrier), so r7's pipeline put a full
//     ~500-900cy drain of wave0's OWN prefetch inside its per-segment path.
//     Now wave0's barrier entry is LDS-only; the staging drain sits on
//     waves 1-3, genuinely overlapped with wave0's scan.
// (b) the greedy mask arithmetic is forced into SGPRs: a_s comes from
//     v_readlane (compiler-provably uniform) so ctz/andn2/bitset compile to
//     1-cy SALU instead of per-lane 64-bit VALU chains. Per keep, only
//     lshr_b64+v_cmp remain vector ops. s_kc is no longer read by wave0.
__global__ __launch_bounds__(256, 1) void scan_kernel(
        const u64* __restrict__ supp, const u32* __restrict__ selkey,
        const float4* __restrict__ selbox, float* __restrict__ out0) {
    int b = blockIdx.x;
    int tid = threadIdx.x;
    int wave = tid >> 6, lane = tid & 63;

    __shared__ u64 rbuf[2][64][33];      // 33.8 KB: double-buffered segment rows (+pad)
    __shared__ u64 lwords[32];           // live words built from selkey
    __shared__ u64 keptmask[SEG_];
    __shared__ int kept[POST_];
    __shared__ int s_kc;

    // live words via ballot: rank r live iff r<PRE_ and key finite (>=0x80000000)
    #pragma unroll
    for (int k = 0; k < 8; ++k) {
        int r = k*256 + tid;
        u32 kk = selkey[b*2048 + r];
        u64 bal = __ballot((r < PRE_) && (kk >= 0x80000000u));
        if (lane == 0) lwords[k*4 + wave] = bal;
    }
    if (tid < SEG_) keptmask[tid] = 0ull;
    if (tid == 0) s_kc = 0;

    const u64* sb = supp + (u64)b*PRE_*32;
    int widx = tid - 64;                 // 0..191 staging index (waves 1-3)

    u64 gr[11];
    if (wave != 0) {
        // prologue: stage seg 0, issue seg 1 (coalesced: f = k*192 + widx)
        #pragma unroll
        for (int k = 0; k < 11; ++k) {
            int f = k*192 + widx;
            if (f < 2048) gr[k] = sb[(u64)(f >> 5)*32 + (f & 31)];
        }
        #pragma unroll
        for (int k = 0; k < 11; ++k) {
            int f = k*192 + widx;
            if (f < 2048) rbuf[0][f >> 5][f & 31] = gr[k];
        }
        #pragma unroll
        for (int k = 0; k < 11; ++k) {
            int f = k*192 + widx;
            if (f < 2048) gr[k] = sb[(u64)(64 + (f >> 5))*32 + (f & 31)];
        }
    }
    __syncthreads();                     // rbuf[0] + lwords ready

    u64 aliveW = 0ull;
    if (wave == 0 && lane < 32) aliveW = lwords[lane];
    int kc = 0;
    int ll = lane & 31;

    for (int g = 0; g < SEG_; ++g) {
        int cur = g & 1;
        if (wave != 0) {
            // 1. write staged seg g+1 (compiler inserts vmcnt wait on gr)
            if (g + 1 < SEG_) {
                #pragma unroll
                for (int k = 0; k < 11; ++k) {
                    int f = k*192 + widx;
                    if (f < 2048) rbuf[cur ^ 1][f >> 5][f & 31] = gr[k];
                }
            }
            // 2. issue coalesced loads for seg g+2 (drained at OUR barrier,
            //    overlapped with wave0's scan of seg g)
            if (g + 2 < SEG_) {
                #pragma unroll
                for (int k = 0; k < 11; ++k) {
                    int f = k*192 + widx;
                    if (f < 2048) {
                        int row = ((g + 2) << 6) + (f >> 5);
                        if (row > PRE_ - 1) row = PRE_ - 1;  // rows >=2000 dead anyway
                        gr[k] = sb[(u64)row*32 + (f & 31)];
                    }
                }
            }
        } else {
            // 3. wave 0: scan seg g entirely from LDS, scalar mask arithmetic
            u64 dj = rbuf[cur][lane][g];          // my diag row == my diag column
            u32 alo = __builtin_amdgcn_readlane((u32)aliveW, g);
            u32 ahi = __builtin_amdgcn_readlane((u32)(aliveW >> 32), g);
            u64 a_s = ((u64)ahi << 32) | alo;     // wave-uniform -> SGPR ops
            if (a_s) {
                u64 ks = 0ull;
                while (a_s && kc < POST_) {
                    int i = (int)__builtin_ctzll(a_s);   // s_ff1 (scalar)
                    ks |= (1ull << i);
                    kc++;
                    u64 km = __ballot(((dj >> i) & 1ull) != 0ull);
                    a_s &= ~km;                          // s_andn2
                    a_s &= ~(1ull << i);
                }
                if (lane == 0) keptmask[g] = ks;
                if (kc < POST_) {
                    // apply kept rows from LDS, 8-wide batches (dup-pad, OR idempotent)
                    u64 t = ks, orr = 0ull;
                    while (t) {
                        int i0 = (int)__builtin_ctzll(t);
                        #define GJ(n) int j##n = t ? (int)__builtin_ctzll(t) : i0; if (t) t &= t - 1;
                        GJ(0) GJ(1) GJ(2) GJ(3) GJ(4) GJ(5) GJ(6) GJ(7)
                        #undef GJ
                        u64 r0 = rbuf[cur][j0][ll];
                        u64 r1 = rbuf[cur][j1][ll];
                        u64 r2 = rbuf[cur][j2][ll];
                        u64 r3 = rbuf[cur][j3][ll];
                        u64 r4 = rbuf[cur][j4][ll];
                        u64 r5 = rbuf[cur][j5][ll];
                        u64 r6 = rbuf[cur][j6][ll];
                        u64 r7 = rbuf[cur][j7][ll];
                        orr |= ((r0 | r1) | (r2 | r3)) | ((r4 | r5) | (r6 | r7));
                    }
                    aliveW &= ~orr;
                }
            }
            if (lane == 0) s_kc = kc;
        }
        __syncthreads();
        bool done = (wave == 0) ? (kc >= POST_) : (s_kc >= POST_);
        if (done) break;
    }

    // reconstruct ordered kept[] from keptmask (ascending rank == greedy order)
    if (wave == 0) {
        u64 w = (lane < 32) ? keptmask[lane] : 0ull;
        int pc = (int)__builtin_popcountll(w);
        int x = pc;
        #pragma unroll
        for (int off = 1; off < 64; off <<= 1) {
            int y = __shfl_up(x, off);
            if (lane >= off) x += y;
        }
        int pr = x - pc;
        u64 t = w;
        int c = 0;
        while (t) {
            int bit = (int)__builtin_ctzll(t);
            t &= t - 1;
            int pos = pr + c; c++;
            if (pos < POST_) kept[pos] = lane*64 + bit;
        }
    }
    __syncthreads();

    int kc2 = s_kc;
    for (int r = tid; r < POST_; r += 256) {
        int i = (r < kc2) ? kept[r] : -1;
        float o1 = 0.f, o2 = 0.f, o3 = 0.f, o4 = 0.f;
        if (i >= 0) {
            float4 bx = selbox[(u64)b*PRE_ + i];
            o1 = bx.x; o2 = bx.y; o3 = bx.z; o4 = bx.w;
        }
        float* rowp = out0 + (u64)(b*POST_ + r)*5;
        rowp[0] = (float)b;
        rowp[1] = o1; rowp[2] = o2; rowp[3] = o3; rowp[4] = o4;
    }
}

extern "C" void kernel_launch(void* const* d_in, const int* in_sizes, int n_in,
                              void* d_out, int out_size, void* d_ws, size_t ws_size,
                              hipStream_t stream) {
    const float* scores  = (const float*)d_in[0];
    const float* deltas  = (const float*)d_in[1];
    const float* anchors = (const float*)d_in[2];
    const float* im_info = (const float*)d_in[3];
    const float* thrp    = (const float*)d_in[7];   // nms_thresh

    float* out0    = (float*)d_out;                 // (16, 300, 5)
    float* outprop = out0 + (u64)B_*POST_*5;        // (16, 147456, 4)

    char* ws = (char*)d_ws;
    u32*    state  = (u32*)   (ws + OFF_STATE);
    u32*    hist0  = (u32*)   (ws + OFF_HIST0);
    u32*    hist1  = (u32*)   (ws + OFF_HIST1);
    u32*    keys   = (u32*)   (ws + OFF_KEYS);
    u64*    cand   = (u64*)   (ws + OFF_CAND);
    float4* selbox = (float4*)(ws + OFF_SELBOX);
    u64*    supp   = (u64*)   (ws + OFF_SUPP);
    u32*    selkey = (u32*)   (ws + OFF_KEYS);      // overlays dead keys region

    hipMemsetAsync(ws, 0, OFF_KEYS, stream);        // state + hist0 + hist1

    decode_kernel<<<B_*256, 576, 0, stream>>>(scores, deltas, anchors, im_info, outprop, keys, hist0);
    hist16_kernel<<<B_*16, 1024, 0, stream>>>(keys, hist0, hist1);
    collect_kernel<<<B_*16, 1024, 0, stream>>>(keys, hist0, hist1, state, cand);
    rank_kernel<<<B_*16, 1024, 0, stream>>>(cand, state, outprop, selbox, selkey);
    iou_kernel<<<B_*250, 256, 0, stream>>>(selbox, thrp, supp);
    scan_kernel<<<B_, 256, 0, stream>>>(supp, selkey, selbox, out0);
}

// Round 10
// 222.403 us; speedup vs baseline: 1.0006x; 1.0006x over previous
//
#include <hip/hip_runtime.h>
#include <stdint.h>

#define B_ 16
#define A_ 9
#define H_ 128
#define W_ 128
#define HW_ (H_*W_)
#define N_ (HW_*A_)          // 147456 proposals per image
#define PRE_ 2000
#define POST_ 300
#define CAND_CAP 4096
#define SEG_ 32              // 2048 / 64 segments for the NMS scan

typedef unsigned int u32;
typedef unsigned long long u64;

// ---- workspace layout (bytes) ----
// [state | hist0 | hist1] zeroed by ONE memsetAsync per launch.
#define OFF_STATE  0ull                               // B*8 u32 (pad to 1024)
#define OFF_HIST0  1024ull                            // B*256 u32 = 16384
#define OFF_HIST1  (OFF_HIST0 + 16384ull)             // B*256 u32 = 16384
#define OFF_KEYS   (OFF_HIST1 + 16384ull)
#define OFF_CAND   (OFF_KEYS + (u64)B_*N_*4)
#define OFF_SELBOX (OFF_CAND + (u64)B_*CAND_CAP*8)
#define OFF_LIVE   (OFF_SELBOX + (u64)B_*PRE_*16)
#define OFF_SUPP   (OFF_LIVE + (u64)B_*32*8)
// end = OFF_SUPP + B*PRE*32*8  (~18.7 MB total)
// NOTE: keys region is dead after collect_kernel; selkey (B*2048*4 = 128KB)
// is overlaid at OFF_KEYS.

__device__ __forceinline__ u32 mono_key(float f) {
    u32 u = __float_as_uint(f);
    return (u & 0x80000000u) ? ~u : (u | 0x80000000u);
}

// wave-level select over a 256-bin histogram: find bin s.t. suffix-count crosses `need`.
// Must be called by a full wave; the matching lane writes {bin, need-above} to out[0..1].
__device__ __forceinline__ void wave_select256(const u32* __restrict__ hh, u32 need,
                                               u32* __restrict__ out) {
    int lane = threadIdx.x & 63;
    uint4 hv = ((const uint4*)hh)[lane];               // bins 4l..4l+3
    u32 psum = hv.x + hv.y + hv.z + hv.w;
    u32 s = psum;                                      // wave-inclusive suffix sum
    #pragma unroll
    for (int off = 1; off < 64; off <<= 1) {
        u32 o = (u32)__shfl_down((int)s, off);
        if (lane + off < 64) s += o;
    }
    u32 S_next = (u32)__shfl_down((int)s, 1);
    if (lane == 63) S_next = 0;
    u32 above[4], cnt[4];
    above[3] = S_next;             cnt[3] = hv.w;
    above[2] = S_next + hv.w;      cnt[2] = hv.z;
    above[1] = above[2] + hv.z;    cnt[1] = hv.y;
    above[0] = above[1] + hv.y;    cnt[0] = hv.x;
    #pragma unroll
    for (int j = 3; j >= 0; --j) {
        if (above[j] < need && above[j] + cnt[j] >= need) {
            out[0] = (u32)(4*lane + j);
            out[1] = need - above[j];
        }
    }
}

// ---------------- stage 1: decode + fg scores + keys + LDS-aggregated 8-bit hist ----------------
// block = 576 threads (wave a=0..8, lane = p offset); coalesced reads AND writes.
__global__ __launch_bounds__(576) void decode_kernel(
        const float* __restrict__ scores,
        const float* __restrict__ deltas,
        const float* __restrict__ anchors,
        const float* __restrict__ im_info,
        float* __restrict__ outprop,
        u32* __restrict__ keys,
        u32* __restrict__ hist0) {
    __shared__ float4 tile[9][65];   // +1 pad
    __shared__ float4 sbase[A_];
    __shared__ u32 h[256];
    int tid = threadIdx.x;
    int a = tid >> 6, lane = tid & 63;
    if (tid < A_) sbase[tid] = ((const float4*)anchors)[tid];  // anchors[p=0] == base anchors
    if (tid < 256) h[tid] = 0;
    __syncthreads();

    int b  = blockIdx.x >> 8;
    int pb = blockIdx.x & 255;
    int p0 = pb << 6;
    int p  = p0 + lane;

    float s0 = scores[((b*2*A_ + a)      << 14) + p];
    float s1 = scores[((b*2*A_ + A_ + a) << 14) + p];
    float m  = fmaxf(s0, s1);
    float e0 = expf(s0 - m);
    float e1 = expf(s1 - m);
    float fg = e1 / (e0 + e1);

    float4 base = sbase[a];
    int ix = p & (W_-1), iy = p >> 7;
    float sx = (float)(ix * 16), sy = (float)(iy * 16);
    float ax1 = base.x + sx, ay1 = base.y + sy, ax2 = base.z + sx, ay2 = base.w + sy;

    float w  = ax2 - ax1 + 1.0f;
    float h_ = ay2 - ay1 + 1.0f;
    float cx = ax1 + 0.5f*w;
    float cy = ay1 + 0.5f*h_;

    const float* dbase = deltas + (u64)(((b*4*A_ + 4*a) << 14) + p);
    float dx = dbase[0];
    float dy = dbase[HW_];
    float dw = dbase[2*HW_];
    float dh = dbase[3*HW_];

    float pcx = dx*w  + cx;
    float pcy = dy*h_ + cy;
    float pw  = expf(dw)*w;
    float ph  = expf(dh)*h_;
    float x1 = pcx - 0.5f*pw, y1 = pcy - 0.5f*ph;
    float x2 = pcx + 0.5f*pw, y2 = pcy + 0.5f*ph;

    float wmax = im_info[b*4 + 1] - 1.0f;
    float hmax = im_info[b*4 + 0] - 1.0f;
    x1 = fminf(fmaxf(x1, 0.0f), wmax);
    y1 = fminf(fmaxf(y1, 0.0f), hmax);
    x2 = fminf(fmaxf(x2, 0.0f), wmax);
    y2 = fminf(fmaxf(y2, 0.0f), hmax);

    tile[a][lane] = make_float4(x1, y1, x2, y2);

    float bw = x2 - x1 + 1.0f;
    float bh = y2 - y1 + 1.0f;
    bool valid = (bw >= 16.0f*im_info[b*4 + 3]) && (bh >= 16.0f*im_info[b*4 + 2]);
    float sc = valid ? fg : -__builtin_inff();
    u32 k = mono_key(sc);
    keys[((u64)(b*A_ + a) << 14) + p] = k;             // coalesced (a,p) layout
    atomicAdd(&h[k >> 24], 1u);                        // LDS-aggregated 8-bit hist
    __syncthreads();

    // coalesced write-back: n = p*9 + a; block covers n in [p0*9, p0*9 + 576)
    int a2 = tid % 9, pl = tid / 9;
    ((float4*)outprop)[(u64)b*N_ + p0*9 + tid] = tile[a2][pl];

    if (tid < 256 && h[tid]) atomicAdd(&hist0[b*256 + tid], h[tid]);
}

// ---------------- stage 2: 16-bit refine histogram (redundant in-block select8) ----------------
__global__ __launch_bounds__(1024) void hist16_kernel(
        const u32* __restrict__ keys, const u32* __restrict__ hist0,
        u32* __restrict__ hist1) {
    int b = blockIdx.x >> 4;
    int slice = blockIdx.x & 15;
    int tid = threadIdx.x;
    __shared__ u32 sel[2];      // {bin8, rem8}
    __shared__ u32 h[256];
    if (tid < 64) wave_select256(hist0 + b*256, (u32)PRE_, sel);
    for (int i = tid; i < 256; i += 1024) h[i] = 0;
    __syncthreads();
    u32 pfx = sel[0];
    const u32* kb = keys + (u64)b*N_ + slice*(N_/16);
    for (int n = tid; n < N_/16; n += 1024) {
        u32 k = kb[n];
        if ((k >> 24) == pfx) atomicAdd(&h[(k >> 16) & 255u], 1u);
    }
    __syncthreads();
    for (int i = tid; i < 256; i += 1024)
        if (h[i]) atomicAdd(&hist1[b*256 + i], h[i]);
}

// ---------------- stage 3: collect all keys >= T (block-aggregated allocation) ----------------
// Candidate order is irrelevant (rank_kernel re-ranks), so positions are
// allocated in bulk: per-thread register key cache + wave scan + LDS block
// scan + ONE global atomicAdd per block (256 total vs ~33k contended RMWs).
__global__ __launch_bounds__(1024) void collect_kernel(
        const u32* __restrict__ keys, const u32* __restrict__ hist0,
        const u32* __restrict__ hist1, u32* __restrict__ state,
        u64* __restrict__ cand) {
    int b = blockIdx.x >> 4;
    int slice = blockIdx.x & 15;
    int tid = threadIdx.x;
    int wave = tid >> 6, lane = tid & 63;
    __shared__ u32 sel8[2], sel16[2];
    __shared__ u32 wbase[16];
    __shared__ u32 s_base;
    if (tid < 64) wave_select256(hist0 + b*256, (u32)PRE_, sel8);
    __syncthreads();
    if (tid < 64) wave_select256(hist1 + b*256, sel8[1], sel16);
    __syncthreads();
    u32 T = (sel8[0] << 24) | (sel16[0] << 16);        // threshold key

    const u32* kb = keys + (u64)b*N_ + slice*(N_/16);
    u64* cb = cand + (u64)b*CAND_CAP;

    // load 9 keys/thread into registers, count matches
    u32 kreg[9];
    int c = 0;
    #pragma unroll
    for (int r = 0; r < 9; ++r) {
        kreg[r] = kb[tid + r*1024];
        c += (kreg[r] >= T) ? 1 : 0;
    }

    // wave inclusive scan of c
    int x = c;
    #pragma unroll
    for (int off = 1; off < 64; off <<= 1) {
        int y = __shfl_up(x, off);
        if (lane >= off) x += y;
    }
    if (lane == 63) wbase[wave] = (u32)x;              // wave total
    __syncthreads();
    if (tid == 0) {
        u32 acc = 0;
        #pragma unroll
        for (int w2 = 0; w2 < 16; ++w2) { u32 t2 = wbase[w2]; wbase[w2] = acc; acc += t2; }
        s_base = acc ? atomicAdd(&state[b*8 + 2], acc) : 0u;
    }
    __syncthreads();

    u32 pos = s_base + wbase[wave] + (u32)(x - c);     // exclusive prefix
    #pragma unroll
    for (int r = 0; r < 9; ++r) {
        if (kreg[r] >= T) {
            int idx = slice*(N_/16) + tid + r*1024;
            u32 n = (u32)((idx & (HW_-1))*A_ + (idx >> 14));  // n = p*9 + a
            if (pos < CAND_CAP) cb[pos] = ((u64)kreg[r] << 32) | (u32)(~n);
            pos++;
        }
    }
}

// ---------------- stage 4: rank-and-scatter (replaces bitonic sort) ----------------
// rank[i] = #{j : cand[j] > cand[i]} over the stored candidates (u64s are
// distinct: low word carries ~n). Scatter selbox[rank] directly. Barrier-free
// O(cnt^2) spread over B*16 blocks = all 256 CUs; LDS reads are wave-uniform
// broadcasts. Winners also record selkey[rank] for the live-word build in scan.
__global__ __launch_bounds__(1024) void rank_kernel(
        const u64* __restrict__ cand, const u32* __restrict__ state,
        const float* __restrict__ outprop,
        float4* __restrict__ selbox, u32* __restrict__ selkey) {
    int bi = blockIdx.x;               // B*16 blocks
    int b = bi >> 4, chunk = bi & 15;
    int tid = threadIdx.x;
    int q = tid >> 8, ti = tid & 255;  // 4 j-quarters x 256 owned candidates
    __shared__ __align__(16) u64 sc[CAND_CAP];
    __shared__ u32 prank[256];

    u32 cnt = state[b*8 + 2];
    if (cnt > CAND_CAP) cnt = CAND_CAP;
    const u64* cb = cand + (u64)b*CAND_CAP;
    for (int j = tid; j < CAND_CAP; j += 1024) sc[j] = (j < (int)cnt) ? cb[j] : 0ull;
    if (tid < 256) prank[tid] = 0;
    __syncthreads();

    int i = (chunk << 8) + ti;
    u64 mine = sc[i];

    // j-quarter over ulonglong2 pairs covering [0, cnt) (pad region is 0)
    int pairs = ((int)cnt + 1) >> 1;
    int pq = (pairs + 3) >> 2;
    int p0 = q * pq;
    int p1 = p0 + pq; if (p1 > pairs) p1 = pairs;
    const ulonglong2* sl = (const ulonglong2*)sc;
    u32 c = 0;
    #pragma unroll 8
    for (int p = p0; p < p1; ++p) {
        ulonglong2 v = sl[p];          // wave-uniform address -> LDS broadcast
        c += (v.x > mine) ? 1u : 0u;
        c += (v.y > mine) ? 1u : 0u;
    }
    if (c) atomicAdd(&prank[ti], c);
    __syncthreads();

    if (q == 0 && i < (int)cnt) {
        u32 rank = prank[ti];
        if (rank < PRE_) {
            u32 n = ~(u32)mine;
            float4 box = ((const float4*)outprop)[(u64)b*N_ + n];
            selbox[(u64)b*PRE_ + rank] = box;
            selkey[b*2048 + rank] = (u32)(mine >> 32);
        }
    }
}

// ---------------- stage 5: upper-triangle IoU suppression bitmask ----------------
// Greedy NMS only reads supp[r][j] for j > r (reference masks ar > i), and
// scan_kernel's eager-apply only reads future words; diag words are always
// inside the strip's starting chunk (256*floor(r/256) <= 64*floor(r/64)).
// So each 8-row strip starts at chunk c0 = rbase>>8: 57% of the chunk work.
// Division is replaced by an EXACT margin test: m = fma(-t, union, inter);
// |m| > 2.0f provably matches fl32(inter/union) > t (union <= 8.4e6 ->
// |q - t| > 2.4e-7, beyond the f32 quotient rounding band). Rare boundary
// lanes fall back to the exact division (wave-coherent branch).
__global__ __launch_bounds__(256) void iou_kernel(
        const float4* __restrict__ selbox, const float* __restrict__ thrp,
        u64* __restrict__ supp) {
    int bi = blockIdx.x;             // B * 250 blocks, 8 rows each
    int b = bi / 250;
    int rbase = (bi % 250) * 8;
    int c0 = rbase >> 8;             // first column chunk (covers full diag word)
    int tid = threadIdx.x;
    __shared__ float4 box[PRE_];
    for (int i = (c0 << 8) + tid; i < PRE_; i += 256) box[i] = selbox[(u64)b*PRE_ + i];
    __syncthreads();
    float thresh = thrp[0];
    int wv = tid >> 6, lane = tid & 63;

    float4 p[8]; float ai[8];
    #pragma unroll
    for (int r = 0; r < 8; ++r) {
        p[r]  = box[rbase + r];
        ai[r] = (p[r].z - p[r].x + 1.f) * (p[r].w - p[r].y + 1.f);
    }
    for (int c = c0; c < 8; ++c) {
        int j = c*256 + tid;
        bool inb = (j < PRE_);
        float4 q = box[inb ? j : 0];
        float aj = (q.z - q.x + 1.f) * (q.w - q.y + 1.f);
        #pragma unroll
        for (int r = 0; r < 8; ++r) {
            float iw = fminf(p[r].z, q.z) - fmaxf(p[r].x, q.x) + 1.f;
            float ih = fminf(p[r].w, q.w) - fmaxf(p[r].y, q.y) + 1.f;
            float inter = fmaxf(iw, 0.f) * ih;   // ih<0 -> inter<=0 -> pred false (exact)
            float su = ai[r] + aj;
            float un = su - inter;               // same assoc as reference
            float m  = __fmaf_rn(-thresh, un, inter);
            bool pred = m > 0.0f;
            if (__any(fabsf(m) <= 2.0f)) {       // rare: exact boundary resolve
                pred = (inter / un) > thresh;
            }
            pred = pred && inb;
            u64 ball = __ballot(pred);
            if (lane == 0)
                supp[((u64)(b*PRE_ + rbase + r))*32 + (c*4 + wv)] = ball;
        }
    }
}

// ---------------- stage 6: role-split pipelined greedy scan, readlane keep-loop ----------------
// ROUND-9: the keep loop is the INVARIANT across four structurally different
// scan versions that all measured 42-47us (r5-r8: gather depth, LDS pipeline,
// role-split all null). Its per-keep __ballot chain (s_ff1 -> v_lshrrev_b64 ->
// v_cmp -> 64b scalar -> SALU interlock -> 2 branches) is the serial cost.
// By symmetry, "whom does kept i suppress in-segment" is ROW i of the diag
// block -- which lane i already holds in dj. So km = readlane64(dj, i): two
// v_readlane_b32 with dynamic SGPR lane index replace shift+cmp+ballot.
// djlo/djhi precomputed per segment so the loop body is s_ff1 + 2 readlane +
// 2 SALU masks.
__global__ __launch_bounds__(256, 1) void scan_kernel(
        const u64* __restrict__ supp, const u32* __restrict__ selkey,
        const float4* __restrict__ selbox, float* __restrict__ out0) {
    int b = blockIdx.x;
    int tid = threadIdx.x;
    int wave = tid >> 6, lane = tid & 63;

    __shared__ u64 rbuf[2][64][33];      // 33.8 KB: double-buffered segment rows (+pad)
    __shared__ u64 lwords[32];           // live words built from selkey
    __shared__ u64 keptmask[SEG_];
    __shared__ int kept[POST_];
    __shared__ int s_kc;

    // live words via ballot: rank r live iff r<PRE_ and key finite (>=0x80000000)
    #pragma unroll
    for (int k = 0; k < 8; ++k) {
        int r = k*256 + tid;
        u32 kk = selkey[b*2048 + r];
        u64 bal = __ballot((r < PRE_) && (kk >= 0x80000000u));
        if (lane == 0) lwords[k*4 + wave] = bal;
    }
    if (tid < SEG_) keptmask[tid] = 0ull;
    if (tid == 0) s_kc = 0;

    const u64* sb = supp + (u64)b*PRE_*32;
    int widx = tid - 64;                 // 0..191 staging index (waves 1-3)

    u64 gr[11];
    if (wave != 0) {
        // prologue: stage seg 0, issue seg 1 (coalesced: f = k*192 + widx)
        #pragma unroll
        for (int k = 0; k < 11; ++k) {
            int f = k*192 + widx;
            if (f < 2048) gr[k] = sb[(u64)(f >> 5)*32 + (f & 31)];
        }
        #pragma unroll
        for (int k = 0; k < 11; ++k) {
            int f = k*192 + widx;
            if (f < 2048) rbuf[0][f >> 5][f & 31] = gr[k];
        }
        #pragma unroll
        for (int k = 0; k < 11; ++k) {
            int f = k*192 + widx;
            if (f < 2048) gr[k] = sb[(u64)(64 + (f >> 5))*32 + (f & 31)];
        }
    }
    __syncthreads();                     // rbuf[0] + lwords ready

    u64 aliveW = 0ull;
    if (wave == 0 && lane < 32) aliveW = lwords[lane];
    int kc = 0;
    int ll = lane & 31;

    for (int g = 0; g < SEG_; ++g) {
        int cur = g & 1;
        if (wave != 0) {
            // 1. write staged seg g+1 (compiler inserts vmcnt wait on gr)
            if (g + 1 < SEG_) {
                #pragma unroll
                for (int k = 0; k < 11; ++k) {
                    int f = k*192 + widx;
                    if (f < 2048) rbuf[cur ^ 1][f >> 5][f & 31] = gr[k];
                }
            }
            // 2. issue coalesced loads for seg g+2 (drained at OUR barrier,
            //    overlapped with wave0's scan of seg g)
            if (g + 2 < SEG_) {
                #pragma unroll
                for (int k = 0; k < 11; ++k) {
                    int f = k*192 + widx;
                    if (f < 2048) {
                        int row = ((g + 2) << 6) + (f >> 5);
                        if (row > PRE_ - 1) row = PRE_ - 1;  // rows >=2000 dead anyway
                        gr[k] = sb[(u64)row*32 + (f & 31)];
                    }
                }
            }
        } else {
            // 3. wave 0: scan seg g from LDS; keep-loop via readlane (no ballot)
            u64 dj = rbuf[cur][lane][g];          // my diag row == my diag column
            u32 djlo = (u32)dj, djhi = (u32)(dj >> 32);
            u32 alo = __builtin_amdgcn_readlane((u32)aliveW, g);
            u32 ahi = __builtin_amdgcn_readlane((u32)(aliveW >> 32), g);
            u64 a_s = ((u64)ahi << 32) | alo;     // wave-uniform -> SGPR ops
            if (a_s) {
                u64 ks = 0ull;
                while (a_s && kc < POST_) {
                    int i = (int)__builtin_ctzll(a_s);           // s_ff1
                    u32 kml = __builtin_amdgcn_readlane(djlo, i); // row i low
                    u32 kmh = __builtin_amdgcn_readlane(djhi, i); // row i high
                    u64 km = ((u64)kmh << 32) | kml;             // = supp row i (symmetry)
                    ks |= (1ull << i);
                    kc++;
                    a_s &= ~km;                                  // s_andn2
                    a_s &= ~(1ull << i);
                }
                if (lane == 0) keptmask[g] = ks;
                if (kc < POST_) {
                    // apply kept rows from LDS, 8-wide batches (dup-pad, OR idempotent)
                    u64 t = ks, orr = 0ull;
                    while (t) {
                        int i0 = (int)__builtin_ctzll(t);
                        #define GJ(n) int j##n = t ? (int)__builtin_ctzll(t) : i0; if (t) t &= t - 1;
                        GJ(0) GJ(1) GJ(2) GJ(3) GJ(4) GJ(5) GJ(6) GJ(7)
                        #undef GJ
                        u64 r0 = rbuf[cur][j0][ll];
                        u64 r1 = rbuf[cur][j1][ll];
                        u64 r2 = rbuf[cur][j2][ll];
                        u64 r3 = rbuf[cur][j3][ll];
                        u64 r4 = rbuf[cur][j4][ll];
                        u64 r5 = rbuf[cur][j5][ll];
                        u64 r6 = rbuf[cur][j6][ll];
                        u64 r7 = rbuf[cur][j7][ll];
                        orr |= ((r0 | r1) | (r2 | r3)) | ((r4 | r5) | (r6 | r7));
                    }
                    aliveW &= ~orr;
                }
            }
            if (lane == 0) s_kc = kc;
        }
        __syncthreads();
        bool done = (wave == 0) ? (kc >= POST_) : (s_kc >= POST_);
        if (done) break;
    }

    // reconstruct ordered kept[] from keptmask (ascending rank == greedy order)
    if (wave == 0) {
        u64 w = (lane < 32) ? keptmask[lane] : 0ull;
        int pc = (int)__builtin_popcountll(w);
        int x = pc;
        #pragma unroll
        for (int off = 1; off < 64; off <<= 1) {
            int y = __shfl_up(x, off);
            if (lane >= off) x += y;
        }
        int pr = x - pc;
        u64 t = w;
        int c = 0;
        while (t) {
            int bit = (int)__builtin_ctzll(t);
            t &= t - 1;
            int pos = pr + c; c++;
            if (pos < POST_) kept[pos] = lane*64 + bit;
        }
    }
    __syncthreads();

    int kc2 = s_kc;
    for (int r = tid; r < POST_; r += 256) {
        int i = (r < kc2) ? kept[r] : -1;
        float o1 = 0.f, o2 = 0.f, o3 = 0.f, o4 = 0.f;
        if (i >= 0) {
            float4 bx = selbox[(u64)b*PRE_ + i];
            o1 = bx.x; o2 = bx.y; o3 = bx.z; o4 = bx.w;
        }
        float* rowp = out0 + (u64)(b*POST_ + r)*5;
        rowp[0] = (float)b;
        rowp[1] = o1; rowp[2] = o2; rowp[3] = o3; rowp[4] = o4;
    }
}

extern "C" void kernel_launch(void* const* d_in, const int* in_sizes, int n_in,
                              void* d_out, int out_size, void* d_ws, size_t ws_size,
                              hipStream_t stream) {
    const float* scores  = (const float*)d_in[0];
    const float* deltas  = (const float*)d_in[1];
    const float* anchors = (const float*)d_in[2];
    const float* im_info = (const float*)d_in[3];
    const float* thrp    = (const float*)d_in[7];   // nms_thresh

    float* out0    = (float*)d_out;                 // (16, 300, 5)
    float* outprop = out0 + (u64)B_*POST_*5;        // (16, 147456, 4)

    char* ws = (char*)d_ws;
    u32*    state  = (u32*)   (ws + OFF_STATE);
    u32*    hist0  = (u32*)   (ws + OFF_HIST0);
    u32*    hist1  = (u32*)   (ws + OFF_HIST1);
    u32*    keys   = (u32*)   (ws + OFF_KEYS);
    u64*    cand   = (u64*)   (ws + OFF_CAND);
    float4* selbox = (float4*)(ws + OFF_SELBOX);
    u64*    supp   = (u64*)   (ws + OFF_SUPP);
    u32*    selkey = (u32*)   (ws + OFF_KEYS);      // overlays dead keys region

    hipMemsetAsync(ws, 0, OFF_KEYS, stream);        // state + hist0 + hist1

    decode_kernel<<<B_*256, 576, 0, stream>>>(scores, deltas, anchors, im_info, outprop, keys, hist0);
    hist16_kernel<<<B_*16, 1024, 0, stream>>>(keys, hist0, hist1);
    collect_kernel<<<B_*16, 1024, 0, stream>>>(keys, hist0, hist1, state, cand);
    rank_kernel<<<B_*16, 1024, 0, stream>>>(cand, state, outprop, selbox, selkey);
    iou_kernel<<<B_*250, 256, 0, stream>>>(selbox, thrp, supp);
    scan_kernel<<<B_, 256, 0, stream>>>(supp, selkey, selbox, out0);
}